// Round 3
// baseline (76.766 us; speedup 1.0000x reference)
//
#include <hip/hip_runtime.h>

#define NF 39
#define NE 40
#define NB 4096
#define NSLOT 1536              // 6 tiles * 256 accumulator slots
#define LSTR 72                 // shorts per padded LDS row (144 B)
#define STAGE_SHORTS (48 * LSTR)
#define K1_BLOCKS 128
#define SPB 32                  // samples per block (4 waves x 8)
#define SPW 8                   // samples per wave

typedef __attribute__((ext_vector_type(8))) short short8;
typedef __attribute__((ext_vector_type(4))) float floatx4;

__device__ __forceinline__ unsigned int f2bf(float f) {
    unsigned int b = __float_as_uint(f);
    b += 0x7FFFu + ((b >> 16) & 1u);   // round-to-nearest-even
    return b >> 16;
}

// ---------------- Kernel 1: gather -> Gram MFMA -> per-block sum/sumsq partials ----------------
__global__ __launch_bounds__(256) void fm_k1(
    const int* __restrict__ inputs, const float* __restrict__ v,
    float* __restrict__ partial)
{
    __shared__ union {
        unsigned short stage[4][STAGE_SHORTS];   // 27648 B (gather staging, per wave)
        float          red[4 * 2 * NSLOT];       // 49152 B (cross-wave reduce)
    } sm;
    __shared__ int idxs[SPB][NF];

    const int t = threadIdx.x, wid = t >> 6, lane = t & 63;
    const int b0 = blockIdx.x * SPB;

    for (int q = t; q < SPB * NF; q += 256) idxs[q / NF][q % NF] = inputs[b0 * NF + q];
    // zero staging once (pad rows 39..47, pad cols 40..63 stay zero across samples)
    unsigned int* z = (unsigned int*)&sm.stage[0][0];
    for (int q = t; q < 4 * STAGE_SHORTS / 2; q += 256) z[q] = 0u;
    __syncthreads();

    floatx4 sum[6] = {}, sq[6] = {};
    unsigned short* st = &sm.stage[wid][0];

    for (int s = 0; s < SPW; ++s) {
        const int* id = idxs[wid * SPW + s];
        for (int q = lane; q < NF * (NE / 4); q += 64) {
            const int r = q / 10, e4 = q - r * 10;
            const float4 val = *reinterpret_cast<const float4*>(v + (size_t)id[r] * NE + e4 * 4);
            uint2 pk;
            pk.x = f2bf(val.x) | (f2bf(val.y) << 16);
            pk.y = f2bf(val.z) | (f2bf(val.w) << 16);
            *reinterpret_cast<uint2*>(st + r * LSTR + e4 * 4) = pk;
        }
        short8 F[2][3];
#pragma unroll
        for (int c = 0; c < 2; ++c)
#pragma unroll
            for (int I = 0; I < 3; ++I) {
                const int row  = (lane & 15) + 16 * I;
                const int eoff = (lane >> 4) * 8 + 32 * c;
                F[c][I] = *reinterpret_cast<const short8*>(st + row * LSTR + eoff);
            }
        floatx4 acc[6] = {};
#pragma unroll
        for (int c = 0; c < 2; ++c) {
            acc[0] = __builtin_amdgcn_mfma_f32_16x16x32_bf16(F[c][0], F[c][0], acc[0], 0, 0, 0);
            acc[1] = __builtin_amdgcn_mfma_f32_16x16x32_bf16(F[c][0], F[c][1], acc[1], 0, 0, 0);
            acc[2] = __builtin_amdgcn_mfma_f32_16x16x32_bf16(F[c][0], F[c][2], acc[2], 0, 0, 0);
            acc[3] = __builtin_amdgcn_mfma_f32_16x16x32_bf16(F[c][1], F[c][1], acc[3], 0, 0, 0);
            acc[4] = __builtin_amdgcn_mfma_f32_16x16x32_bf16(F[c][1], F[c][2], acc[4], 0, 0, 0);
            acc[5] = __builtin_amdgcn_mfma_f32_16x16x32_bf16(F[c][2], F[c][2], acc[5], 0, 0, 0);
        }
#pragma unroll
        for (int tl = 0; tl < 6; ++tl) {
            sum[tl] += acc[tl];
            sq[tl]  += acc[tl] * acc[tl];
        }
    }

    __syncthreads();   // all staging dead -> reuse as reduce buffer
    float* rw = &sm.red[wid * 2 * NSLOT];
#pragma unroll
    for (int tl = 0; tl < 6; ++tl) {
        *reinterpret_cast<floatx4*>(rw + tl * 256 + lane * 4)         = sum[tl];
        *reinterpret_cast<floatx4*>(rw + NSLOT + tl * 256 + lane * 4) = sq[tl];
    }
    __syncthreads();
    float* po = partial + (size_t)blockIdx.x * (2 * NSLOT);
    for (int j = t; j < 2 * NSLOT; j += 256)
        po[j] = sm.red[j] + sm.red[2 * NSLOT + j] + sm.red[4 * NSLOT + j] + sm.red[6 * NSLOT + j];
}

// ---------------- Kernel 2: finalize mean / scale per slot ----------------
__global__ __launch_bounds__(256) void fm_k2(
    const float* __restrict__ partial, const float* __restrict__ ew,
    float* __restrict__ meanArr, float* __restrict__ scaleArr)
{
    const int slot = blockIdx.x * 256 + threadIdx.x;   // 6 blocks x 256
    float s1 = 0.f, s2 = 0.f;
#pragma unroll 8
    for (int i = 0; i < K1_BLOCKS; ++i) {
        const float* p = partial + (size_t)i * 2 * NSLOT;
        s1 += p[slot];
        s2 += p[NSLOT + slot];
    }
    const float m   = s1 * (1.0f / NB);
    const float var = s2 * (1.0f / NB) - m * m;
    const int tile = slot >> 8;
    const int l    = (slot & 255) >> 2;
    const int q    = slot & 3;
    const int TI[6] = {0, 0, 0, 1, 1, 2};
    const int TJ[6] = {0, 1, 2, 1, 2, 2};
    const int gi = 16 * TI[tile] + ((l >> 4) << 2) + q;
    const int gj = 16 * TJ[tile] + (l & 15);
    float scl = 0.0f;
    if (gi < gj && gj < NF) {
        const int p = 38 * gi - (gi * (gi - 1)) / 2 + (gj - gi - 1);
        scl = ew[p] * rsqrtf(var + 1.0e-3f);
    }
    meanArr[slot]  = m;
    scaleArr[slot] = scl;
}

// ---------------- Kernel 3: re-gather + Gram MFMA + normalize-reduce + first-order ----------------
__global__ __launch_bounds__(256) void fm_k3(
    const int* __restrict__ inputs, const float* __restrict__ w,
    const float* __restrict__ v, const float* __restrict__ meanArr,
    const float* __restrict__ scaleArr, const float* __restrict__ bias,
    float* __restrict__ out)
{
    __shared__ unsigned short stage[4][STAGE_SHORTS];
    __shared__ int idxs[SPB][NF];
    const int t = threadIdx.x, wid = t >> 6, lane = t & 63;
    const int b0 = blockIdx.x * SPB;

    for (int q = t; q < SPB * NF; q += 256) idxs[q / NF][q % NF] = inputs[b0 * NF + q];
    unsigned int* z = (unsigned int*)&stage[0][0];
    for (int q = t; q < 4 * STAGE_SHORTS / 2; q += 256) z[q] = 0u;
    __syncthreads();

    // hoist normalization fragments (same slots every sample)
    floatx4 mf[6], sf[6];
#pragma unroll
    for (int tl = 0; tl < 6; ++tl) {
        mf[tl] = *reinterpret_cast<const floatx4*>(meanArr  + tl * 256 + lane * 4);
        sf[tl] = *reinterpret_cast<const floatx4*>(scaleArr + tl * 256 + lane * 4);
    }
    const float bs = bias[0];
    unsigned short* st = &stage[wid][0];

    for (int s = 0; s < SPW; ++s) {
        const int smp = wid * SPW + s;
        const int* id = idxs[smp];
        for (int q = lane; q < NF * (NE / 4); q += 64) {
            const int r = q / 10, e4 = q - r * 10;
            const float4 val = *reinterpret_cast<const float4*>(v + (size_t)id[r] * NE + e4 * 4);
            uint2 pk;
            pk.x = f2bf(val.x) | (f2bf(val.y) << 16);
            pk.y = f2bf(val.z) | (f2bf(val.w) << 16);
            *reinterpret_cast<uint2*>(st + r * LSTR + e4 * 4) = pk;
        }
        short8 F[2][3];
#pragma unroll
        for (int c = 0; c < 2; ++c)
#pragma unroll
            for (int I = 0; I < 3; ++I) {
                const int row  = (lane & 15) + 16 * I;
                const int eoff = (lane >> 4) * 8 + 32 * c;
                F[c][I] = *reinterpret_cast<const short8*>(st + row * LSTR + eoff);
            }
        floatx4 acc[6] = {};
#pragma unroll
        for (int c = 0; c < 2; ++c) {
            acc[0] = __builtin_amdgcn_mfma_f32_16x16x32_bf16(F[c][0], F[c][0], acc[0], 0, 0, 0);
            acc[1] = __builtin_amdgcn_mfma_f32_16x16x32_bf16(F[c][0], F[c][1], acc[1], 0, 0, 0);
            acc[2] = __builtin_amdgcn_mfma_f32_16x16x32_bf16(F[c][0], F[c][2], acc[2], 0, 0, 0);
            acc[3] = __builtin_amdgcn_mfma_f32_16x16x32_bf16(F[c][1], F[c][1], acc[3], 0, 0, 0);
            acc[4] = __builtin_amdgcn_mfma_f32_16x16x32_bf16(F[c][1], F[c][2], acc[4], 0, 0, 0);
            acc[5] = __builtin_amdgcn_mfma_f32_16x16x32_bf16(F[c][2], F[c][2], acc[5], 0, 0, 0);
        }
        float tot = (lane < NF) ? w[id[lane]] : 0.0f;   // first-order term
#pragma unroll
        for (int tl = 0; tl < 6; ++tl)
#pragma unroll
            for (int q = 0; q < 4; ++q)
                tot += (acc[tl][q] - mf[tl][q]) * sf[tl][q];
#pragma unroll
        for (int o = 32; o > 0; o >>= 1) tot += __shfl_down(tot, o, 64);
        if (lane == 0) out[b0 + smp] = tot + bs;
    }
}

extern "C" void kernel_launch(void* const* d_in, const int* in_sizes, int n_in,
                              void* d_out, int out_size, void* d_ws, size_t ws_size,
                              hipStream_t stream)
{
    const int*   inputs = (const int*)  d_in[0];
    // d_in[1]=rows, d_in[2]=cols reproduced in-kernel (validated R2)
    const float* w      = (const float*)d_in[3];
    const float* v      = (const float*)d_in[4];
    const float* bias   = (const float*)d_in[5];
    const float* ew     = (const float*)d_in[6];
    float*       out    = (float*)      d_out;

    // ws layout (floats): partial[K1_BLOCKS*2*NSLOT] | mean[NSLOT] | scale[NSLOT]
    float* partial = (float*)d_ws;
    float* meanA   = partial + (size_t)K1_BLOCKS * 2 * NSLOT;
    float* scaleA  = meanA + NSLOT;

    fm_k1<<<K1_BLOCKS,     256, 0, stream>>>(inputs, v, partial);
    fm_k2<<<NSLOT / 256,   256, 0, stream>>>(partial, ew, meanA, scaleA);
    fm_k3<<<NB / SPB,      256, 0, stream>>>(inputs, w, v, meanA, scaleA, bias, out);
}

// Round 4
// 34.156 us; speedup vs baseline: 2.2475x; 2.2475x over previous
//
#include <hip/hip_runtime.h>

#define NF 39
#define NE 40
#define NB 4096
#define NSLOT 1536            // 6 tiles * 256 accumulator slots
#define K1_BLOCKS 512
#define SPW 2                 // samples per wave
#define SPB 8                 // samples per block (4 waves * SPW)
#define K2A_COLB 12           // 3072 cols / 256
#define K2A_ROWG 8            // 512 rows / 64

typedef __attribute__((ext_vector_type(8))) short short8;
typedef __attribute__((ext_vector_type(4))) float floatx4;

__device__ __forceinline__ unsigned int f2bf(float f) {
    unsigned int b = __float_as_uint(f);
    b += 0x7FFFu + ((b >> 16) & 1u);   // round-to-nearest-even
    return b >> 16;
}

__device__ __forceinline__ short8 pack8(float4 a, float4 b) {
    union { unsigned int u[4]; short8 s; } o;
    o.u[0] = f2bf(a.x) | (f2bf(a.y) << 16);
    o.u[1] = f2bf(a.z) | (f2bf(a.w) << 16);
    o.u[2] = f2bf(b.x) | (f2bf(b.y) << 16);
    o.u[3] = f2bf(b.z) | (f2bf(b.w) << 16);
    return o.s;
}

// Direct-to-register fragment gather for one sample. Lane covers rows
// (lane&15)+16I, elem chunks (lane>>4)*8 (c=0) and 32+(lane>>4)*8 (c=1).
__device__ __forceinline__ void load_frags(
    const int* __restrict__ ip, const float* __restrict__ v,
    int rbase, int ehalf, short8 F0[3], short8 F1[3])
{
    const float4 zero4 = {0.f, 0.f, 0.f, 0.f};
#pragma unroll
    for (int I = 0; I < 3; ++I) {
        const int r = rbase + 16 * I;
        const bool vr = (r < NF);
        const int id = vr ? ip[r] : 0;
        const float* vrow = v + (size_t)id * NE;
        const float4 a  = vr ? *reinterpret_cast<const float4*>(vrow + ehalf * 8)     : zero4;
        const float4 bq = vr ? *reinterpret_cast<const float4*>(vrow + ehalf * 8 + 4) : zero4;
        F0[I] = pack8(a, bq);
        const bool v1 = vr && (ehalf == 0);
        const float4 c_ = v1 ? *reinterpret_cast<const float4*>(vrow + 32) : zero4;
        const float4 d_ = v1 ? *reinterpret_cast<const float4*>(vrow + 36) : zero4;
        F1[I] = pack8(c_, d_);
    }
}

__device__ __forceinline__ void gram_mfma(const short8 F0[3], const short8 F1[3], floatx4 acc[6])
{
    acc[0] = __builtin_amdgcn_mfma_f32_16x16x32_bf16(F0[0], F0[0], acc[0], 0, 0, 0);
    acc[1] = __builtin_amdgcn_mfma_f32_16x16x32_bf16(F0[0], F0[1], acc[1], 0, 0, 0);
    acc[2] = __builtin_amdgcn_mfma_f32_16x16x32_bf16(F0[0], F0[2], acc[2], 0, 0, 0);
    acc[3] = __builtin_amdgcn_mfma_f32_16x16x32_bf16(F0[1], F0[1], acc[3], 0, 0, 0);
    acc[4] = __builtin_amdgcn_mfma_f32_16x16x32_bf16(F0[1], F0[2], acc[4], 0, 0, 0);
    acc[5] = __builtin_amdgcn_mfma_f32_16x16x32_bf16(F0[2], F0[2], acc[5], 0, 0, 0);
    acc[0] = __builtin_amdgcn_mfma_f32_16x16x32_bf16(F1[0], F1[0], acc[0], 0, 0, 0);
    acc[1] = __builtin_amdgcn_mfma_f32_16x16x32_bf16(F1[0], F1[1], acc[1], 0, 0, 0);
    acc[2] = __builtin_amdgcn_mfma_f32_16x16x32_bf16(F1[0], F1[2], acc[2], 0, 0, 0);
    acc[3] = __builtin_amdgcn_mfma_f32_16x16x32_bf16(F1[1], F1[1], acc[3], 0, 0, 0);
    acc[4] = __builtin_amdgcn_mfma_f32_16x16x32_bf16(F1[1], F1[2], acc[4], 0, 0, 0);
    acc[5] = __builtin_amdgcn_mfma_f32_16x16x32_bf16(F1[2], F1[2], acc[5], 0, 0, 0);
}

// ---------------- Kernel 1: reg-gather Gram + per-block sum/sumsq partials ----------------
__global__ __launch_bounds__(256) void fm_k1(
    const int* __restrict__ inputs, const float* __restrict__ v,
    float* __restrict__ partial)
{
    __shared__ float red[4 * 2 * NSLOT];   // 48 KB cross-wave reduce
    const int t = threadIdx.x, wid = t >> 6, lane = t & 63;
    const int rbase = lane & 15, ehalf = lane >> 4;
    const int b0 = blockIdx.x * SPB;

    floatx4 sum[6] = {}, sq[6] = {};
#pragma unroll
    for (int s = 0; s < SPW; ++s) {
        const int* ip = inputs + (size_t)(b0 + wid * SPW + s) * NF;
        short8 F0[3], F1[3];
        load_frags(ip, v, rbase, ehalf, F0, F1);
        floatx4 acc[6] = {};
        gram_mfma(F0, F1, acc);
#pragma unroll
        for (int tl = 0; tl < 6; ++tl) {
            sum[tl] += acc[tl];
            sq[tl]  += acc[tl] * acc[tl];
        }
    }

    float* rw = &red[wid * 2 * NSLOT];
#pragma unroll
    for (int tl = 0; tl < 6; ++tl) {
        *reinterpret_cast<floatx4*>(rw + tl * 256 + lane * 4)         = sum[tl];
        *reinterpret_cast<floatx4*>(rw + NSLOT + tl * 256 + lane * 4) = sq[tl];
    }
    __syncthreads();
    float* po = partial + (size_t)blockIdx.x * (2 * NSLOT);
    for (int j = t; j < 2 * NSLOT; j += 256)
        po[j] = red[j] + red[2 * NSLOT + j] + red[4 * NSLOT + j] + red[6 * NSLOT + j];
}

// ---------------- Kernel 2a: coalesced column partial-reduce over 64-row groups ----------------
__global__ __launch_bounds__(256) void fm_k2a(
    const float* __restrict__ partial, float* __restrict__ partial2)
{
    const int col = blockIdx.x * 256 + threadIdx.x;
    const int r0  = blockIdx.y * 64;
    float s = 0.0f;
#pragma unroll 8
    for (int r = 0; r < 64; ++r)
        s += partial[(size_t)(r0 + r) * (2 * NSLOT) + col];
    partial2[(size_t)blockIdx.y * (2 * NSLOT) + col] = s;
}

// ---------------- Kernel 2b: finalize mean / scale per slot ----------------
__global__ __launch_bounds__(256) void fm_k2b(
    const float* __restrict__ partial2, const float* __restrict__ ew,
    float* __restrict__ meanArr, float* __restrict__ scaleArr)
{
    const int slot = blockIdx.x * 256 + threadIdx.x;   // 6 blocks x 256
    float s1 = 0.f, s2 = 0.f;
#pragma unroll
    for (int ry = 0; ry < K2A_ROWG; ++ry) {
        s1 += partial2[(size_t)ry * (2 * NSLOT) + slot];
        s2 += partial2[(size_t)ry * (2 * NSLOT) + NSLOT + slot];
    }
    const float m   = s1 * (1.0f / NB);
    const float var = s2 * (1.0f / NB) - m * m;
    const int tile = slot >> 8;
    const int l    = (slot & 255) >> 2;
    const int q    = slot & 3;
    const int TI[6] = {0, 0, 0, 1, 1, 2};
    const int TJ[6] = {0, 1, 2, 1, 2, 2};
    const int gi = 16 * TI[tile] + ((l >> 4) << 2) + q;
    const int gj = 16 * TJ[tile] + (l & 15);
    float scl = 0.0f;
    if (gi < gj && gj < NF) {
        const int p = 38 * gi - (gi * (gi - 1)) / 2 + (gj - gi - 1);
        scl = ew[p] * rsqrtf(var + 1.0e-3f);
    }
    meanArr[slot]  = m;
    scaleArr[slot] = scl;
}

// ---------------- Kernel 3: reg-gather Gram + normalize-reduce + first-order ----------------
__global__ __launch_bounds__(256) void fm_k3(
    const int* __restrict__ inputs, const float* __restrict__ w,
    const float* __restrict__ v, const float* __restrict__ meanArr,
    const float* __restrict__ scaleArr, const float* __restrict__ bias,
    float* __restrict__ out)
{
    const int t = threadIdx.x, wid = t >> 6, lane = t & 63;
    const int rbase = lane & 15, ehalf = lane >> 4;
    const int b0 = blockIdx.x * SPB;

    floatx4 mf[6], sf[6];
#pragma unroll
    for (int tl = 0; tl < 6; ++tl) {
        mf[tl] = *reinterpret_cast<const floatx4*>(meanArr  + tl * 256 + lane * 4);
        sf[tl] = *reinterpret_cast<const floatx4*>(scaleArr + tl * 256 + lane * 4);
    }
    const float bs = bias[0];

#pragma unroll
    for (int s = 0; s < SPW; ++s) {
        const int smp = b0 + wid * SPW + s;
        const int* ip = inputs + (size_t)smp * NF;
        short8 F0[3], F1[3];
        load_frags(ip, v, rbase, ehalf, F0, F1);
        floatx4 acc[6] = {};
        gram_mfma(F0, F1, acc);
        float tot = (lane < NF) ? w[ip[lane]] : 0.0f;   // first-order term
#pragma unroll
        for (int tl = 0; tl < 6; ++tl)
#pragma unroll
            for (int q = 0; q < 4; ++q)
                tot += (acc[tl][q] - mf[tl][q]) * sf[tl][q];
#pragma unroll
        for (int o = 32; o > 0; o >>= 1) tot += __shfl_down(tot, o, 64);
        if (lane == 0) out[smp] = tot + bs;
    }
}

extern "C" void kernel_launch(void* const* d_in, const int* in_sizes, int n_in,
                              void* d_out, int out_size, void* d_ws, size_t ws_size,
                              hipStream_t stream)
{
    const int*   inputs = (const int*)  d_in[0];
    // d_in[1]=rows, d_in[2]=cols reproduced in-kernel (validated R2/R3)
    const float* w      = (const float*)d_in[3];
    const float* v      = (const float*)d_in[4];
    const float* bias   = (const float*)d_in[5];
    const float* ew     = (const float*)d_in[6];
    float*       out    = (float*)      d_out;

    // ws (floats): partial[512*3072] | partial2[8*3072] | mean[1536] | scale[1536]
    float* partial  = (float*)d_ws;
    float* partial2 = partial + (size_t)K1_BLOCKS * 2 * NSLOT;
    float* meanA    = partial2 + (size_t)K2A_ROWG * 2 * NSLOT;
    float* scaleA   = meanA + NSLOT;

    fm_k1 <<<K1_BLOCKS, 256, 0, stream>>>(inputs, v, partial);
    fm_k2a<<<dim3(K2A_COLB, K2A_ROWG), 256, 0, stream>>>(partial, partial2);
    fm_k2b<<<NSLOT / 256, 256, 0, stream>>>(partial2, ew, meanA, scaleA);
    fm_k3 <<<NB / SPB, 256, 0, stream>>>(inputs, w, v, meanA, scaleA, bias, out);
}